// Round 3
// baseline (957.647 us; speedup 1.0000x reference)
//
#include <hip/hip_runtime.h>
#include <math.h>

#define N0 1048576
#define N1 65536
#define N2 4096
#define DEG0 16
#define DEG1 10
#define D_IN 128
#define D_H 256
#define D_OUT 47

typedef unsigned int uint32;
typedef __attribute__((ext_vector_type(8))) short bf16x8;
typedef __attribute__((ext_vector_type(4))) float f32x4;

__device__ __forceinline__ unsigned short f2b(float x) {
    uint32 u = __float_as_uint(x);
    return (unsigned short)((u + 0x7fffu + ((u >> 16) & 1u)) >> 16);
}
__device__ __forceinline__ float b2f(unsigned short h) {
    return __uint_as_float(((uint32)h) << 16);
}
__device__ __forceinline__ float gelu_exact(float x) {
    return 0.5f * x * (1.0f + erff(x * 0.70710678118654752f));
}
// split 8 fp32 into hi/lo bf16 fragments (a = elems 0..3, b = 4..7)
__device__ __forceinline__ void split8(float4 a, float4 b, bf16x8& fh, bf16x8& fl) {
    float t[8] = {a.x, a.y, a.z, a.w, b.x, b.y, b.z, b.w};
#pragma unroll
    for (int j = 0; j < 8; ++j) {
        unsigned short h = f2b(t[j]);
        fh[j] = (short)h;
        fl[j] = (short)f2b(t[j] - b2f(h));
    }
}

// ---------------------------------------------------------------------------
// One-shot weight prep: split Wl0, Wr0, Wl1, Wr1, Wo into hi/lo bf16 planes.
// ---------------------------------------------------------------------------
__global__ __launch_bounds__(256) void prep_weights(
    const float4* __restrict__ Wl0, const float4* __restrict__ Wr0,
    const float4* __restrict__ Wl1, const float4* __restrict__ Wr1,
    const float4* __restrict__ Wo,
    ushort4* __restrict__ wl0h, ushort4* __restrict__ wl0l,
    ushort4* __restrict__ wr0h, ushort4* __restrict__ wr0l,
    ushort4* __restrict__ wl1h, ushort4* __restrict__ wl1l,
    ushort4* __restrict__ wr1h, ushort4* __restrict__ wr1l,
    ushort4* __restrict__ woh,  ushort4* __restrict__ wol)
{
    const int b = blockIdx.x, t = threadIdx.x;
    const float4* src; ushort4 *dh, *dl; int i, n4;
    if (b < 32)       { src = Wl0; dh = wl0h; dl = wl0l; i = b * 256 + t;         n4 = 8192;  }
    else if (b < 64)  { src = Wr0; dh = wr0h; dl = wr0l; i = (b - 32) * 256 + t;  n4 = 8192;  }
    else if (b < 128) { src = Wl1; dh = wl1h; dl = wl1l; i = (b - 64) * 256 + t;  n4 = 16384; }
    else if (b < 192) { src = Wr1; dh = wr1h; dl = wr1l; i = (b - 128) * 256 + t; n4 = 16384; }
    else              { src = Wo;  dh = woh;  dl = wol;  i = (b - 192) * 256 + t; n4 = 3008;  }
    if (i < n4) {
        float4 v = src[i];
        ushort4 h, l;
        h.x = f2b(v.x); l.x = f2b(v.x - b2f(h.x));
        h.y = f2b(v.y); l.y = f2b(v.y - b2f(h.y));
        h.z = f2b(v.z); l.z = f2b(v.z - b2f(h.z));
        h.w = f2b(v.w); l.w = f2b(v.w - b2f(h.w));
        dh[i] = h; dl[i] = l;
    }
}

// ---------------------------------------------------------------------------
// Fused layer 0: gather-mean(x) + [mean|x] @ [Wl0;Wr0]^T + bias, gelu ->
// h0 hi/lo bf16 planes. BM=64, 256 threads = 4 waves, each wave one 16-row
// m-tile x all 256 n. A-fragments built directly in registers: lane (l16,q)
// owns A[m=l16][k=c*32+q*8+j] (verified MFMA layout, learn_hip m89).
// ---------------------------------------------------------------------------
__global__ __launch_bounds__(256) void layer0_fused(
    const float* __restrict__ x, const int* __restrict__ idx,
    const unsigned short* __restrict__ Blh, const unsigned short* __restrict__ Bll,
    const unsigned short* __restrict__ Brh, const unsigned short* __restrict__ Brl,
    const float* __restrict__ bias,
    unsigned short* __restrict__ oh, unsigned short* __restrict__ ol)
{
    const int tid  = threadIdx.x;
    const int w    = tid >> 6;
    const int lane = tid & 63;
    const int quad = lane >> 4;
    const int l16  = lane & 15;
    const int m    = blockIdx.x * 64 + w * 16 + l16;   // dst row for this lane

    // ---- phase 1: gather-mean into this lane's fragment k-slice ----
    float mean[4][8];
#pragma unroll
    for (int c = 0; c < 4; ++c)
#pragma unroll
        for (int j = 0; j < 8; ++j) mean[c][j] = 0.f;

    int srcs[DEG0];
    {
        const int4* ip = (const int4*)(idx + (size_t)m * DEG0);
#pragma unroll
        for (int q = 0; q < 4; ++q) {
            int4 v = ip[q];
            srcs[4 * q + 0] = v.x; srcs[4 * q + 1] = v.y;
            srcs[4 * q + 2] = v.z; srcs[4 * q + 3] = v.w;
        }
    }
#pragma unroll
    for (int e = 0; e < DEG0; ++e) {
        const float* row = x + (size_t)srcs[e] * D_IN + quad * 8;
#pragma unroll
        for (int c = 0; c < 4; ++c) {
            float4 v0 = *(const float4*)(row + c * 32);
            float4 v1 = *(const float4*)(row + c * 32 + 4);
            mean[c][0] += v0.x; mean[c][1] += v0.y; mean[c][2] += v0.z; mean[c][3] += v0.w;
            mean[c][4] += v1.x; mean[c][5] += v1.y; mean[c][6] += v1.z; mean[c][7] += v1.w;
        }
    }
    bf16x8 a1h[4], a1l[4];
#pragma unroll
    for (int c = 0; c < 4; ++c)
#pragma unroll
        for (int j = 0; j < 8; ++j) {
            float v = mean[c][j] * 0.0625f;
            unsigned short h = f2b(v);
            a1h[c][j] = (short)h;
            a1l[c][j] = (short)f2b(v - b2f(h));
        }

    // ---- phase 2: MFMA over K=256 (mean vs Wl0, then x[m] vs Wr0) ----
    f32x4 acc[16];
#pragma unroll
    for (int nt = 0; nt < 16; ++nt) acc[nt] = (f32x4)0.f;

#pragma unroll
    for (int c = 0; c < 4; ++c) {
        const int ko = c * 32 + quad * 8;
#pragma unroll
        for (int nt = 0; nt < 16; ++nt) {
            const size_t bo_ = (size_t)(nt * 16 + l16) * D_IN + ko;
            bf16x8 bh = *(const bf16x8*)(Blh + bo_);
            bf16x8 bl = *(const bf16x8*)(Bll + bo_);
            acc[nt] = __builtin_amdgcn_mfma_f32_16x16x32_bf16(a1l[c], bh, acc[nt], 0, 0, 0);
            acc[nt] = __builtin_amdgcn_mfma_f32_16x16x32_bf16(a1h[c], bl, acc[nt], 0, 0, 0);
            acc[nt] = __builtin_amdgcn_mfma_f32_16x16x32_bf16(a1h[c], bh, acc[nt], 0, 0, 0);
        }
    }
    const float* xrow = x + (size_t)m * D_IN + quad * 8;
#pragma unroll
    for (int c = 0; c < 4; ++c) {
        float4 v0 = *(const float4*)(xrow + c * 32);
        float4 v1 = *(const float4*)(xrow + c * 32 + 4);
        bf16x8 ah, al;
        split8(v0, v1, ah, al);
        const int ko = c * 32 + quad * 8;
#pragma unroll
        for (int nt = 0; nt < 16; ++nt) {
            const size_t bo_ = (size_t)(nt * 16 + l16) * D_IN + ko;
            bf16x8 bh = *(const bf16x8*)(Brh + bo_);
            bf16x8 bl = *(const bf16x8*)(Brl + bo_);
            acc[nt] = __builtin_amdgcn_mfma_f32_16x16x32_bf16(al, bh, acc[nt], 0, 0, 0);
            acc[nt] = __builtin_amdgcn_mfma_f32_16x16x32_bf16(ah, bl, acc[nt], 0, 0, 0);
            acc[nt] = __builtin_amdgcn_mfma_f32_16x16x32_bf16(ah, bh, acc[nt], 0, 0, 0);
        }
    }

    // ---- epilogue: D layout col=l16, row=quad*4+r ----
    const int row0 = blockIdx.x * 64 + w * 16 + quad * 4;
#pragma unroll
    for (int nt = 0; nt < 16; ++nt) {
        const int col = nt * 16 + l16;
        const float bb = bias[col];
#pragma unroll
        for (int r = 0; r < 4; ++r) {
            float v = gelu_exact(acc[nt][r] + bb);
            unsigned short h = f2b(v);
            const size_t o = (size_t)(row0 + r) * D_H + col;
            oh[o] = h;
            ol[o] = f2b(v - b2f(h));
        }
    }
}

// ---------------------------------------------------------------------------
// Fused layer 1: gather-mean(h0 planes) + [mean|h0] @ [Wl1;Wr1]^T + gelu ->
// h1 planes. BM=32, 128 threads = 2 waves. K=256 per operand half.
// ---------------------------------------------------------------------------
__global__ __launch_bounds__(128) void layer1_fused(
    const unsigned short* __restrict__ fh, const unsigned short* __restrict__ fl,
    const int* __restrict__ idx,
    const unsigned short* __restrict__ Blh, const unsigned short* __restrict__ Bll,
    const unsigned short* __restrict__ Brh, const unsigned short* __restrict__ Brl,
    const float* __restrict__ bias,
    unsigned short* __restrict__ oh, unsigned short* __restrict__ ol)
{
    const int tid  = threadIdx.x;
    const int w    = tid >> 6;
    const int lane = tid & 63;
    const int quad = lane >> 4;
    const int l16  = lane & 15;
    const int m    = blockIdx.x * 32 + w * 16 + l16;

    float mean[8][8];
#pragma unroll
    for (int c = 0; c < 8; ++c)
#pragma unroll
        for (int j = 0; j < 8; ++j) mean[c][j] = 0.f;

    int srcs[DEG1];
#pragma unroll
    for (int e = 0; e < DEG1; ++e) srcs[e] = idx[(size_t)m * DEG1 + e];

#pragma unroll
    for (int e = 0; e < DEG1; ++e) {
        const unsigned short* rh = fh + (size_t)srcs[e] * D_H + quad * 8;
        const unsigned short* rl = fl + (size_t)srcs[e] * D_H + quad * 8;
#pragma unroll
        for (int c = 0; c < 8; ++c) {
            bf16x8 hv = *(const bf16x8*)(rh + c * 32);
            bf16x8 lv = *(const bf16x8*)(rl + c * 32);
#pragma unroll
            for (int j = 0; j < 8; ++j)
                mean[c][j] += b2f((unsigned short)hv[j]) + b2f((unsigned short)lv[j]);
        }
    }
    bf16x8 a1h[8], a1l[8];
#pragma unroll
    for (int c = 0; c < 8; ++c)
#pragma unroll
        for (int j = 0; j < 8; ++j) {
            float v = mean[c][j] * 0.1f;
            unsigned short h = f2b(v);
            a1h[c][j] = (short)h;
            a1l[c][j] = (short)f2b(v - b2f(h));
        }

    f32x4 acc[16];
#pragma unroll
    for (int nt = 0; nt < 16; ++nt) acc[nt] = (f32x4)0.f;

#pragma unroll
    for (int c = 0; c < 8; ++c) {
        const int ko = c * 32 + quad * 8;
#pragma unroll
        for (int nt = 0; nt < 16; ++nt) {
            const size_t bo_ = (size_t)(nt * 16 + l16) * D_H + ko;
            bf16x8 bh = *(const bf16x8*)(Blh + bo_);
            bf16x8 bl = *(const bf16x8*)(Bll + bo_);
            acc[nt] = __builtin_amdgcn_mfma_f32_16x16x32_bf16(a1l[c], bh, acc[nt], 0, 0, 0);
            acc[nt] = __builtin_amdgcn_mfma_f32_16x16x32_bf16(a1h[c], bl, acc[nt], 0, 0, 0);
            acc[nt] = __builtin_amdgcn_mfma_f32_16x16x32_bf16(a1h[c], bh, acc[nt], 0, 0, 0);
        }
    }
    const unsigned short* arh = fh + (size_t)m * D_H + quad * 8;
    const unsigned short* arl = fl + (size_t)m * D_H + quad * 8;
#pragma unroll
    for (int c = 0; c < 8; ++c) {
        bf16x8 ah = *(const bf16x8*)(arh + c * 32);
        bf16x8 al = *(const bf16x8*)(arl + c * 32);
        const int ko = c * 32 + quad * 8;
#pragma unroll
        for (int nt = 0; nt < 16; ++nt) {
            const size_t bo_ = (size_t)(nt * 16 + l16) * D_H + ko;
            bf16x8 bh = *(const bf16x8*)(Brh + bo_);
            bf16x8 bl = *(const bf16x8*)(Brl + bo_);
            acc[nt] = __builtin_amdgcn_mfma_f32_16x16x32_bf16(al, bh, acc[nt], 0, 0, 0);
            acc[nt] = __builtin_amdgcn_mfma_f32_16x16x32_bf16(ah, bl, acc[nt], 0, 0, 0);
            acc[nt] = __builtin_amdgcn_mfma_f32_16x16x32_bf16(ah, bh, acc[nt], 0, 0, 0);
        }
    }

    const int row0 = blockIdx.x * 32 + w * 16 + quad * 4;
#pragma unroll
    for (int nt = 0; nt < 16; ++nt) {
        const int col = nt * 16 + l16;
        const float bb = bias[col];
#pragma unroll
        for (int r = 0; r < 4; ++r) {
            float v = gelu_exact(acc[nt][r] + bb);
            unsigned short h = f2b(v);
            const size_t o = (size_t)(row0 + r) * D_H + col;
            oh[o] = h;
            ol[o] = f2b(v - b2f(h));
        }
    }
}

// ---------------------------------------------------------------------------
// Projection: out[4096 x 47] = h1 @ Wo^T + bo. BM=32, N padded to 64 in
// fragments (zero B rows beyond 47), masked fp32 stores.
// ---------------------------------------------------------------------------
__global__ __launch_bounds__(128) void proj_fused(
    const unsigned short* __restrict__ fh, const unsigned short* __restrict__ fl,
    const unsigned short* __restrict__ Wh, const unsigned short* __restrict__ Wl_,
    const float* __restrict__ bo, float* __restrict__ out)
{
    const int tid  = threadIdx.x;
    const int w    = tid >> 6;
    const int lane = tid & 63;
    const int quad = lane >> 4;
    const int l16  = lane & 15;
    const int m    = blockIdx.x * 32 + w * 16 + l16;

    f32x4 acc[4];
#pragma unroll
    for (int nt = 0; nt < 4; ++nt) acc[nt] = (f32x4)0.f;

    const unsigned short* arh = fh + (size_t)m * D_H + quad * 8;
    const unsigned short* arl = fl + (size_t)m * D_H + quad * 8;
#pragma unroll
    for (int c = 0; c < 8; ++c) {
        bf16x8 ah = *(const bf16x8*)(arh + c * 32);
        bf16x8 al = *(const bf16x8*)(arl + c * 32);
        const int ko = c * 32 + quad * 8;
#pragma unroll
        for (int nt = 0; nt < 4; ++nt) {
            const int n = nt * 16 + l16;
            bf16x8 bh = {0, 0, 0, 0, 0, 0, 0, 0};
            bf16x8 bl = {0, 0, 0, 0, 0, 0, 0, 0};
            if (n < D_OUT) {
                const size_t o = (size_t)n * D_H + ko;
                bh = *(const bf16x8*)(Wh + o);
                bl = *(const bf16x8*)(Wl_ + o);
            }
            acc[nt] = __builtin_amdgcn_mfma_f32_16x16x32_bf16(al, bh, acc[nt], 0, 0, 0);
            acc[nt] = __builtin_amdgcn_mfma_f32_16x16x32_bf16(ah, bl, acc[nt], 0, 0, 0);
            acc[nt] = __builtin_amdgcn_mfma_f32_16x16x32_bf16(ah, bh, acc[nt], 0, 0, 0);
        }
    }

    const int row0 = blockIdx.x * 32 + w * 16 + quad * 4;
#pragma unroll
    for (int nt = 0; nt < 4; ++nt) {
        const int col = nt * 16 + l16;
        if (col < D_OUT) {
            const float bb = bo[col];
#pragma unroll
            for (int r = 0; r < 4; ++r)
                out[(size_t)(row0 + r) * D_OUT + col] = acc[nt][r] + bb;
        }
    }
}

extern "C" void kernel_launch(void* const* d_in, const int* in_sizes, int n_in,
                              void* d_out, int out_size, void* d_ws, size_t ws_size,
                              hipStream_t stream)
{
    const float* x        = (const float*)d_in[0];
    const int*   indices0 = (const int*)d_in[1];
    const int*   indices1 = (const int*)d_in[3];
    const float* Wl0 = (const float*)d_in[5];
    const float* bl0 = (const float*)d_in[6];
    const float* Wr0 = (const float*)d_in[7];
    const float* Wl1 = (const float*)d_in[8];
    const float* bl1 = (const float*)d_in[9];
    const float* Wr1 = (const float*)d_in[10];
    const float* Wo  = (const float*)d_in[11];
    const float* bo  = (const float*)d_in[12];
    float* out = (float*)d_out;

    unsigned short* p = (unsigned short*)d_ws;
    unsigned short* h0h  = p; p += (size_t)N1 * D_H;
    unsigned short* h0l  = p; p += (size_t)N1 * D_H;
    unsigned short* h1h  = p; p += (size_t)N2 * D_H;
    unsigned short* h1l  = p; p += (size_t)N2 * D_H;
    unsigned short* wl0h = p; p += 256 * 128;
    unsigned short* wl0l = p; p += 256 * 128;
    unsigned short* wr0h = p; p += 256 * 128;
    unsigned short* wr0l = p; p += 256 * 128;
    unsigned short* wl1h = p; p += 256 * 256;
    unsigned short* wl1l = p; p += 256 * 256;
    unsigned short* wr1h = p; p += 256 * 256;
    unsigned short* wr1l = p; p += 256 * 256;
    unsigned short* woh  = p; p += 47 * 256;
    unsigned short* wol  = p; p += 47 * 256;

    prep_weights<<<204, 256, 0, stream>>>(
        (const float4*)Wl0, (const float4*)Wr0, (const float4*)Wl1,
        (const float4*)Wr1, (const float4*)Wo,
        (ushort4*)wl0h, (ushort4*)wl0l, (ushort4*)wr0h, (ushort4*)wr0l,
        (ushort4*)wl1h, (ushort4*)wl1l, (ushort4*)wr1h, (ushort4*)wr1l,
        (ushort4*)woh,  (ushort4*)wol);

    layer0_fused<<<N1 / 64, 256, 0, stream>>>(
        x, indices0, wl0h, wl0l, wr0h, wr0l, bl0, h0h, h0l);

    layer1_fused<<<N2 / 32, 128, 0, stream>>>(
        h0h, h0l, indices1, wl1h, wl1l, wr1h, wr1l, bl1, h1h, h1l);

    proj_fused<<<N2 / 32, 128, 0, stream>>>(
        h1h, h1l, woh, wol, bo, out);
}